// Round 7
// baseline (391.511 us; speedup 1.0000x reference)
//
#include <hip/hip_runtime.h>
#include <stdint.h>

#define HIDDEN 512
#define NLAYERS 3
#define KNN 8
#define CAP 64
#define EPSV 1e-5f
#define GRID 32
#define NCELL (GRID * GRID)

typedef unsigned long long u64;
typedef __attribute__((ext_vector_type(8))) short short8;   // 8 bf16 = 4 VGPRs
typedef __attribute__((ext_vector_type(4))) float f32x4;    // MFMA acc

__device__ inline unsigned short f2bf(float x) {  // RNE fp32 -> bf16 bits
  union { float f; unsigned u; } v; v.f = x;
  unsigned r = v.u + 0x7FFFu + ((v.u >> 16) & 1u);
  return (unsigned short)(r >> 16);
}
__device__ inline float bf2f(unsigned short u) {
  return __uint_as_float((unsigned)u << 16);
}

// ---------------------------------------------------------------------------
// Grid build: one 1024-thread block per batch. Counting sort into 32x32 cells.
// Sorted order (scoord/sorig) is the processing order of the whole pipeline.
// ---------------------------------------------------------------------------
__global__ __launch_bounds__(1024) void grid_build_kernel(
    const float2* __restrict__ coords, int* __restrict__ cell_start,
    float2* __restrict__ scoord, int* __restrict__ sorig, int N) {
  __shared__ int hist[NCELL];
  __shared__ int offs[NCELL];
  int b = blockIdx.x;
  int t = threadIdx.x;
  hist[t] = 0;
  __syncthreads();
  const float2* cb = coords + (size_t)b * N;
  int mycell[4];
#pragma unroll
  for (int r = 0; r < 4; ++r) {
    int i = t + r * 1024;
    float2 c = cb[i];
    int cx = (int)(c.x * GRID); cx = cx < 0 ? 0 : (cx > GRID - 1 ? GRID - 1 : cx);
    int cy = (int)(c.y * GRID); cy = cy < 0 ? 0 : (cy > GRID - 1 ? GRID - 1 : cy);
    mycell[r] = cy * GRID + cx;
    atomicAdd(&hist[mycell[r]], 1);
  }
  __syncthreads();
  int v = hist[t];
  offs[t] = v;
  __syncthreads();
  for (int d = 1; d < NCELL; d <<= 1) {
    int add = (t >= d) ? offs[t - d] : 0;
    __syncthreads();
    offs[t] += add;
    __syncthreads();
  }
  int excl = offs[t] - v;
  cell_start[(size_t)b * (NCELL + 1) + t] = excl;
  if (t == 0) cell_start[(size_t)b * (NCELL + 1) + NCELL] = N;
  hist[t] = excl;
  __syncthreads();
#pragma unroll
  for (int r = 0; r < 4; ++r) {
    int i = t + r * 1024;
    int pos = atomicAdd(&hist[mycell[r]], 1);
    scoord[(size_t)b * N + pos] = cb[i];
    sorig[(size_t)b * N + pos] = i;
  }
}

// ---------------------------------------------------------------------------
// Gang-of-8 grid kNN (checker-bit-exact d2; see round-5 comments).
// ---------------------------------------------------------------------------
__global__ __launch_bounds__(256) void knn_grid_kernel(
    const int* __restrict__ cell_start, const float2* __restrict__ scoord,
    const int* __restrict__ sorig, int* __restrict__ knn_s, int N, int BN) {
  int gang = (blockIdx.x * blockDim.x + threadIdx.x) >> 3;
  int sub = threadIdx.x & 7;
  if (gang >= BN) return;
  int b = gang / N;
  float2 cn = scoord[gang];
  float sqn = __fmaf_rn(cn.y, cn.y, __fmul_rn(cn.x, cn.x));
  int cx = (int)(cn.x * GRID); cx = cx < 0 ? 0 : (cx > GRID - 1 ? GRID - 1 : cx);
  int cy = (int)(cn.y * GRID); cy = cy < 0 ? 0 : (cy > GRID - 1 ? GRID - 1 : cy);
  const int* cs = cell_start + (size_t)b * (NCELL + 1);
  const float2* sc = scoord + (size_t)b * N;
  const int* so = sorig + (size_t)b * N;

  u64 list[KNN + 1];
#pragma unroll
  for (int j = 0; j <= KNN; ++j) list[j] = ~0ull;

  auto scan_cell = [&](int ux, int uy) {
    int c = uy * GRID + ux;
    int s = cs[c], e = cs[c + 1];
    for (int p = s + sub; p < e; p += 8) {
      float2 cm = sc[p];
      float sqm = __fmaf_rn(cm.y, cm.y, __fmul_rn(cm.x, cm.x));
      float dot = __fmaf_rn(cn.y, cm.y, __fmul_rn(cn.x, cm.x));
      float d2 = __fsub_rn(__fadd_rn(sqn, sqm), __fmul_rn(2.0f, dot));
      unsigned ub = __float_as_uint(d2);
      unsigned k32 = (ub & 0x80000000u) ? ~ub : (ub | 0x80000000u);
      u64 key = ((u64)k32 << 24) | ((u64)(unsigned)so[p] << 12) | (u64)(unsigned)p;
      if (key < list[KNN]) {
        u64 cur = key;
#pragma unroll
        for (int j = 0; j <= KNN; ++j) {
          u64 lo = list[j] < cur ? list[j] : cur;
          u64 hi = list[j] < cur ? cur : list[j];
          list[j] = lo;
          cur = hi;
        }
      }
    }
  };

  for (int q = 0; q <= GRID; ++q) {
    if (q == 0) {
      scan_cell(cx, cy);
    } else {
      int x0 = cx - q, x1 = cx + q, y0 = cy - q, y1 = cy + q;
      int xa = x0 < 0 ? 0 : x0, xb_ = x1 > GRID - 1 ? GRID - 1 : x1;
      for (int ux = xa; ux <= xb_; ++ux) {
        if (y0 >= 0) scan_cell(ux, y0);
        if (y1 <= GRID - 1) scan_cell(ux, y1);
      }
      int ya = (y0 + 1) < 0 ? 0 : y0 + 1, yb = (y1 - 1) > GRID - 1 ? GRID - 1 : y1 - 1;
      for (int uy = ya; uy <= yb; ++uy) {
        if (x0 >= 0) scan_cell(x0, uy);
        if (x1 <= GRID - 1) scan_cell(x1, uy);
      }
      float bound = (float)q * (1.0f / GRID);
      float thr = bound * bound - 1e-5f;
      int cntn = 0;
#pragma unroll
      for (int j = 0; j <= KNN; ++j) {
        unsigned k32 = (unsigned)(list[j] >> 24);
        float d2v = (k32 >= 0x80000000u) ? __uint_as_float(k32 & 0x7FFFFFFFu)
                                         : -__uint_as_float(~k32);
        cntn += (list[j] != ~0ull && d2v < thr) ? 1 : 0;
      }
#pragma unroll
      for (int o = 1; o < 8; o <<= 1) cntn += __shfl_xor(cntn, o, 64);
      if (cntn >= 9) break;
    }
  }

  for (int r = 0; r <= KNN; ++r) {
    u64 cand = list[0];
    u64 mn = cand;
#pragma unroll
    for (int o = 1; o < 8; o <<= 1) {
      u64 v = __shfl_xor(mn, o, 64);
      mn = v < mn ? v : mn;
    }
    if (cand == mn) {
#pragma unroll
      for (int j = 0; j < KNN; ++j) list[j] = list[j + 1];
      list[KNN] = ~0ull;
      if (r > 0) knn_s[(size_t)gang * KNN + (r - 1)] = (int)(mn & 0xFFFull);
    }
  }
}

// ---------------------------------------------------------------------------
__global__ __launch_bounds__(256) void rev_build_kernel(const int* __restrict__ knn,
                                                        int* __restrict__ cnt,
                                                        int* __restrict__ rev,
                                                        int N, int BN) {
  int e = blockIdx.x * blockDim.x + threadIdx.x;
  if (e >= BN * KNN) return;
  int bn = e >> 3;
  int m = knn[e];
  int b = bn / N;
  int gm = b * N + m;
  int pos = atomicAdd(&cnt[gm], 1);
  if (pos < CAP) rev[(size_t)gm * CAP + pos] = bn - b * N;
}

// ---------------------------------------------------------------------------
// Initial features -> bf16, permuted to sorted order.
// ---------------------------------------------------------------------------
__global__ __launch_bounds__(128) void x2bf_perm_kernel(const float* __restrict__ x,
                                                        const int* __restrict__ sorig,
                                                        unsigned short* __restrict__ xs,
                                                        int N) {
  int row = blockIdx.x;
  int b = row / N;
  int src = b * N + sorig[row];
  int t = threadIdx.x;
  float4 v = ((const float4*)(x + (size_t)src * HIDDEN))[t];
  ushort4 o;
  o.x = f2bf(v.x); o.y = f2bf(v.y); o.z = f2bf(v.z); o.w = f2bf(v.w);
  ((ushort4*)(xs + (size_t)row * HIDDEN))[t] = o;
}

// ---------------------------------------------------------------------------
// Aggregation in sorted space (neighbors index-local -> L2 resident).
// ---------------------------------------------------------------------------
__global__ __launch_bounds__(128) void agg_kernel(const unsigned short* __restrict__ x,
                                                  const int* __restrict__ knn,
                                                  const int* __restrict__ cnt,
                                                  const int* __restrict__ rev,
                                                  unsigned short* __restrict__ aggb,
                                                  int N) {
  int bn = blockIdx.x;
  int b = bn / N;
  int t = threadIdx.x;
  const int* my = knn + (size_t)bn * KNN;
  int nb[KNN];
#pragma unroll
  for (int j = 0; j < KNN; ++j) nb[j] = my[j];
  const unsigned short* xb = x + (size_t)b * N * HIDDEN;
  float4 acc = {0.f, 0.f, 0.f, 0.f};
#pragma unroll
  for (int j = 0; j < KNN; ++j) {
    ushort4 v = ((const ushort4*)(xb + (size_t)nb[j] * HIDDEN))[t];
    acc.x += bf2f(v.x); acc.y += bf2f(v.y); acc.z += bf2f(v.z); acc.w += bf2f(v.w);
  }
  int indeg = cnt[bn];
  if (indeg > CAP) indeg = CAP;
  const int* rv = rev + (size_t)bn * CAP;
  for (int i = 0; i < indeg; ++i) {
    int r = rv[i];
    bool dup = false;
#pragma unroll
    for (int j = 0; j < KNN; ++j) dup = dup || (r == nb[j]);
    if (!dup) {
      ushort4 v = ((const ushort4*)(xb + (size_t)r * HIDDEN))[t];
      acc.x += bf2f(v.x); acc.y += bf2f(v.y); acc.z += bf2f(v.z); acc.w += bf2f(v.w);
    }
  }
  ushort4 o;
  o.x = f2bf(acc.x); o.y = f2bf(acc.y); o.z = f2bf(acc.z); o.w = f2bf(acc.w);
  ((ushort4*)(aggb + (size_t)bn * HIDDEN))[t] = o;
}

// ---------------------------------------------------------------------------
// W convert+transpose: W[l][k][n] fp32 -> Wt[l][n][k] bf16.
// ---------------------------------------------------------------------------
__global__ __launch_bounds__(256) void wconv_kernel(const float* __restrict__ W,
                                                    unsigned short* __restrict__ Wt) {
  __shared__ unsigned short tile[64][65];
  int l = blockIdx.x >> 6;
  int t6 = blockIdx.x & 63;
  int k0 = (t6 >> 3) * 64, n0 = (t6 & 7) * 64;
  const float* Wl = W + (size_t)l * HIDDEN * HIDDEN;
  unsigned short* Wtl = Wt + (size_t)l * HIDDEN * HIDDEN;
  int t = threadIdx.x;
#pragma unroll
  for (int r = 0; r < 4; ++r) {
    int row = (t >> 4) + r * 16;
    int col = (t & 15) * 4;
    float4 v = *(const float4*)(Wl + (size_t)(k0 + row) * HIDDEN + n0 + col);
    tile[col + 0][row] = f2bf(v.x);
    tile[col + 1][row] = f2bf(v.y);
    tile[col + 2][row] = f2bf(v.z);
    tile[col + 3][row] = f2bf(v.w);
  }
  __syncthreads();
#pragma unroll
  for (int r = 0; r < 4; ++r) {
    int row = (t >> 4) + r * 16;
    int col = (t & 15) * 4;
    ushort4 o;
    o.x = tile[row][col + 0]; o.y = tile[row][col + 1];
    o.z = tile[row][col + 2]; o.w = tile[row][col + 3];
    *(ushort4*)(Wtl + (size_t)(n0 + row) * HIDDEN + k0 + col) = o;
  }
}

// ---------------------------------------------------------------------------
// FUSED GEMM + bias + LayerNorm + ReLU + residual (+ final scatter).
// Block: 64 rows x ALL 512 cols, 512 threads = 8 waves, wave w owns the
// 64-col stripe [64w, 64w+64). Per wave 4x4 MFMA 16x16x32 tiles (64 acc).
// LDS: As 64x40 (5 KB) + Bs 512x40 (40 KB) + red 4 KB = 49 KB.
// Epilogue: bias -> per-lane partial row sums -> shfl_xor over 16-lane col
// group -> LDS cross-wave reduce -> fp32 LN (same numerics as split version)
// -> ReLU -> bf16 residual -> write xs (bf16) or scatter fp32 to out.
// ---------------------------------------------------------------------------
__global__ __launch_bounds__(512) void gemm_ln_fused_kernel(
    const unsigned short* __restrict__ A,    // aggb [BN][512] bf16
    const unsigned short* __restrict__ Wt,   // [n][k] bf16
    const float* __restrict__ bias,
    const float* __restrict__ g,
    const float* __restrict__ be,
    unsigned short* __restrict__ xs,         // bf16 state (residual in / x out)
    float* __restrict__ out,
    const int* __restrict__ sorig,
    int N, int addres, int final_) {
  __shared__ unsigned short As[64 * 40];
  __shared__ unsigned short Bs[512 * 40];
  __shared__ float red[8][64][2];
  int t = threadIdx.x;
  int m0 = blockIdx.x * 64;
  int w = t >> 6, lane = t & 63;
  int lm = lane & 15, q = lane >> 4;

  f32x4 acc[4][4];
#pragma unroll
  for (int i = 0; i < 4; ++i)
#pragma unroll
    for (int j = 0; j < 4; ++j) acc[i][j] = (f32x4){0.f, 0.f, 0.f, 0.f};

  int arow = t >> 2;          // 0..63 (t<256)
  int acol = (t & 3) * 8;
  int brow0 = t >> 2;         // 0..127
  int bcol = (t & 3) * 8;

  for (int k0 = 0; k0 < HIDDEN; k0 += 32) {
    uint4 av;
    if (t < 256) av = *(const uint4*)(A + (size_t)(m0 + arow) * HIDDEN + k0 + acol);
    uint4 bv[4];
#pragma unroll
    for (int r = 0; r < 4; ++r)
      bv[r] = *(const uint4*)(Wt + (size_t)(brow0 + r * 128) * HIDDEN + k0 + bcol);
    __syncthreads();
    if (t < 256) *(uint4*)(As + arow * 40 + acol) = av;
#pragma unroll
    for (int r = 0; r < 4; ++r)
      *(uint4*)(Bs + (brow0 + r * 128) * 40 + bcol) = bv[r];
    __syncthreads();
    short8 af[4], bf[4];
#pragma unroll
    for (int i = 0; i < 4; ++i)
      af[i] = *(const short8*)(As + (i * 16 + lm) * 40 + q * 8);
#pragma unroll
    for (int j = 0; j < 4; ++j)
      bf[j] = *(const short8*)(Bs + (w * 64 + j * 16 + lm) * 40 + q * 8);
#pragma unroll
    for (int i = 0; i < 4; ++i)
#pragma unroll
      for (int j = 0; j < 4; ++j)
        acc[i][j] = __builtin_amdgcn_mfma_f32_16x16x32_bf16(af[i], bf[j], acc[i][j], 0, 0, 0);
  }

  // ---- epilogue: bias + row-sum partials
  float bv4[4], gv[4], bev[4];
#pragma unroll
  for (int j = 0; j < 4; ++j) {
    int col = w * 64 + j * 16 + lm;
    bv4[j] = bias[col]; gv[j] = g[col]; bev[j] = be[col];
  }
  float s[4][4], ss[4][4];
#pragma unroll
  for (int i = 0; i < 4; ++i)
#pragma unroll
    for (int r = 0; r < 4; ++r) { s[i][r] = 0.f; ss[i][r] = 0.f; }
#pragma unroll
  for (int i = 0; i < 4; ++i)
#pragma unroll
    for (int j = 0; j < 4; ++j)
#pragma unroll
      for (int r = 0; r < 4; ++r) {
        float v = acc[i][j][r] + bv4[j];
        acc[i][j][r] = v;
        s[i][r] += v;
        ss[i][r] += v * v;
      }
#pragma unroll
  for (int i = 0; i < 4; ++i)
#pragma unroll
    for (int r = 0; r < 4; ++r) {
#pragma unroll
      for (int o = 1; o < 16; o <<= 1) {
        s[i][r] += __shfl_xor(s[i][r], o, 64);
        ss[i][r] += __shfl_xor(ss[i][r], o, 64);
      }
    }
  if (lm == 0) {
#pragma unroll
    for (int i = 0; i < 4; ++i)
#pragma unroll
      for (int r = 0; r < 4; ++r) {
        int rloc = i * 16 + q * 4 + r;
        red[w][rloc][0] = s[i][r];
        red[w][rloc][1] = ss[i][r];
      }
  }
  __syncthreads();

#pragma unroll
  for (int i = 0; i < 4; ++i) {
#pragma unroll
    for (int r = 0; r < 4; ++r) {
      int rloc = i * 16 + q * 4 + r;
      float S = 0.f, SS = 0.f;
#pragma unroll
      for (int ww = 0; ww < 8; ++ww) { S += red[ww][rloc][0]; SS += red[ww][rloc][1]; }
      float mu = S * (1.0f / HIDDEN);
      float var = SS * (1.0f / HIDDEN) - mu * mu;
      float inv = rsqrtf(var + EPSV);
      int row_g = m0 + rloc;
      if (final_) {
        int bb = row_g / N;
        size_t dst = (size_t)(bb * N + sorig[row_g]) * HIDDEN;
#pragma unroll
        for (int j = 0; j < 4; ++j) {
          int col = w * 64 + j * 16 + lm;
          float v = fmaxf((acc[i][j][r] - mu) * inv * gv[j] + bev[j], 0.f);
          if (addres) v += bf2f(xs[(size_t)row_g * HIDDEN + col]);
          out[dst + col] = v;
        }
      } else {
#pragma unroll
        for (int j = 0; j < 4; ++j) {
          int col = w * 64 + j * 16 + lm;
          float v = fmaxf((acc[i][j][r] - mu) * inv * gv[j] + bev[j], 0.f);
          if (addres) v += bf2f(xs[(size_t)row_g * HIDDEN + col]);
          xs[(size_t)row_g * HIDDEN + col] = f2bf(v);
        }
      }
    }
  }
}

// ---------------------------------------------------------------------------
extern "C" void kernel_launch(void* const* d_in, const int* in_sizes, int n_in,
                              void* d_out, int out_size, void* d_ws, size_t ws_size,
                              hipStream_t stream) {
  const float* nf = (const float*)d_in[0];
  const float2* coords = (const float2*)d_in[1];
  const float* Wall = (const float*)d_in[2];
  const float* ball = (const float*)d_in[3];
  const float* gall = (const float*)d_in[4];
  const float* beall = (const float*)d_in[5];
  float* out = (float*)d_out;

  int BN = in_sizes[0] / HIDDEN;  // 16384
  int N = 4096;
  int B = BN / N;

  char* ws = (char*)d_ws;
  size_t off = 0;
  auto alloc = [&](size_t bytes) -> void* {
    off = (off + 255) & ~(size_t)255;
    void* p = ws + off;
    off += bytes;
    return p;
  };
  int* knn_s = (int*)alloc((size_t)BN * KNN * sizeof(int));
  int* cnt = (int*)alloc((size_t)BN * sizeof(int));
  int* rev = (int*)alloc((size_t)BN * CAP * sizeof(int));
  unsigned short* aggb = (unsigned short*)alloc((size_t)BN * HIDDEN * sizeof(unsigned short));
  unsigned short* Wt = (unsigned short*)alloc((size_t)NLAYERS * HIDDEN * HIDDEN * sizeof(unsigned short));
  unsigned short* xs = (unsigned short*)alloc((size_t)BN * HIDDEN * sizeof(unsigned short));
  int* cell_start = (int*)alloc((size_t)B * (NCELL + 1) * sizeof(int));
  float2* scoord = (float2*)alloc((size_t)BN * sizeof(float2));
  int* sorig = (int*)alloc((size_t)BN * sizeof(int));

  hipMemsetAsync(cnt, 0, (size_t)BN * sizeof(int), stream);
  grid_build_kernel<<<B, 1024, 0, stream>>>(coords, cell_start, scoord, sorig, N);
  knn_grid_kernel<<<(BN * 8 + 255) / 256, 256, 0, stream>>>(cell_start, scoord, sorig, knn_s, N, BN);
  rev_build_kernel<<<(BN * KNN) / 256, 256, 0, stream>>>(knn_s, cnt, rev, N, BN);
  wconv_kernel<<<NLAYERS * 64, 256, 0, stream>>>(Wall, Wt);
  x2bf_perm_kernel<<<BN, 128, 0, stream>>>(nf, sorig, xs, N);

  for (int l = 0; l < NLAYERS; ++l) {
    agg_kernel<<<BN, 128, 0, stream>>>(xs, knn_s, cnt, rev, aggb, N);
    gemm_ln_fused_kernel<<<BN / 64, 512, 0, stream>>>(
        aggb, Wt + (size_t)l * HIDDEN * HIDDEN, ball + (size_t)l * HIDDEN,
        gall + (size_t)l * HIDDEN, beall + (size_t)l * HIDDEN,
        xs, out, sorig, N, l > 0, l == NLAYERS - 1);
  }
}

// Round 8
// 286.740 us; speedup vs baseline: 1.3654x; 1.3654x over previous
//
#include <hip/hip_runtime.h>
#include <stdint.h>

#define HIDDEN 512
#define NLAYERS 3
#define KNN 8
#define CAP 64
#define EPSV 1e-5f
#define GRID 32
#define NCELL (GRID * GRID)

typedef unsigned long long u64;
typedef __attribute__((ext_vector_type(8))) short short8;   // 8 bf16 = 4 VGPRs
typedef __attribute__((ext_vector_type(4))) float f32x4;    // MFMA acc

__device__ inline unsigned short f2bf(float x) {  // RNE fp32 -> bf16 bits
  union { float f; unsigned u; } v; v.f = x;
  unsigned r = v.u + 0x7FFFu + ((v.u >> 16) & 1u);
  return (unsigned short)(r >> 16);
}
__device__ inline float bf2f(unsigned short u) {
  return __uint_as_float((unsigned)u << 16);
}

// ---------------------------------------------------------------------------
// Grid build: one 1024-thread block per batch. Counting sort into 32x32 cells.
// Sorted order (scoord/sorig) is the processing order of the whole pipeline.
// ---------------------------------------------------------------------------
__global__ __launch_bounds__(1024) void grid_build_kernel(
    const float2* __restrict__ coords, int* __restrict__ cell_start,
    float2* __restrict__ scoord, int* __restrict__ sorig, int N) {
  __shared__ int hist[NCELL];
  __shared__ int offs[NCELL];
  int b = blockIdx.x;
  int t = threadIdx.x;
  hist[t] = 0;
  __syncthreads();
  const float2* cb = coords + (size_t)b * N;
  int mycell[4];
#pragma unroll
  for (int r = 0; r < 4; ++r) {
    int i = t + r * 1024;
    float2 c = cb[i];
    int cx = (int)(c.x * GRID); cx = cx < 0 ? 0 : (cx > GRID - 1 ? GRID - 1 : cx);
    int cy = (int)(c.y * GRID); cy = cy < 0 ? 0 : (cy > GRID - 1 ? GRID - 1 : cy);
    mycell[r] = cy * GRID + cx;
    atomicAdd(&hist[mycell[r]], 1);
  }
  __syncthreads();
  int v = hist[t];
  offs[t] = v;
  __syncthreads();
  for (int d = 1; d < NCELL; d <<= 1) {
    int add = (t >= d) ? offs[t - d] : 0;
    __syncthreads();
    offs[t] += add;
    __syncthreads();
  }
  int excl = offs[t] - v;
  cell_start[(size_t)b * (NCELL + 1) + t] = excl;
  if (t == 0) cell_start[(size_t)b * (NCELL + 1) + NCELL] = N;
  hist[t] = excl;
  __syncthreads();
#pragma unroll
  for (int r = 0; r < 4; ++r) {
    int i = t + r * 1024;
    int pos = atomicAdd(&hist[mycell[r]], 1);
    scoord[(size_t)b * N + pos] = cb[i];
    sorig[(size_t)b * N + pos] = i;
  }
}

// ---------------------------------------------------------------------------
// Gang-of-8 grid kNN (checker-bit-exact d2; see round-5 comments).
// ---------------------------------------------------------------------------
__global__ __launch_bounds__(256) void knn_grid_kernel(
    const int* __restrict__ cell_start, const float2* __restrict__ scoord,
    const int* __restrict__ sorig, int* __restrict__ knn_s, int N, int BN) {
  int gang = (blockIdx.x * blockDim.x + threadIdx.x) >> 3;
  int sub = threadIdx.x & 7;
  if (gang >= BN) return;
  int b = gang / N;
  float2 cn = scoord[gang];
  float sqn = __fmaf_rn(cn.y, cn.y, __fmul_rn(cn.x, cn.x));
  int cx = (int)(cn.x * GRID); cx = cx < 0 ? 0 : (cx > GRID - 1 ? GRID - 1 : cx);
  int cy = (int)(cn.y * GRID); cy = cy < 0 ? 0 : (cy > GRID - 1 ? GRID - 1 : cy);
  const int* cs = cell_start + (size_t)b * (NCELL + 1);
  const float2* sc = scoord + (size_t)b * N;
  const int* so = sorig + (size_t)b * N;

  u64 list[KNN + 1];
#pragma unroll
  for (int j = 0; j <= KNN; ++j) list[j] = ~0ull;

  auto scan_cell = [&](int ux, int uy) {
    int c = uy * GRID + ux;
    int s = cs[c], e = cs[c + 1];
    for (int p = s + sub; p < e; p += 8) {
      float2 cm = sc[p];
      float sqm = __fmaf_rn(cm.y, cm.y, __fmul_rn(cm.x, cm.x));
      float dot = __fmaf_rn(cn.y, cm.y, __fmul_rn(cn.x, cm.x));
      float d2 = __fsub_rn(__fadd_rn(sqn, sqm), __fmul_rn(2.0f, dot));
      unsigned ub = __float_as_uint(d2);
      unsigned k32 = (ub & 0x80000000u) ? ~ub : (ub | 0x80000000u);
      u64 key = ((u64)k32 << 24) | ((u64)(unsigned)so[p] << 12) | (u64)(unsigned)p;
      if (key < list[KNN]) {
        u64 cur = key;
#pragma unroll
        for (int j = 0; j <= KNN; ++j) {
          u64 lo = list[j] < cur ? list[j] : cur;
          u64 hi = list[j] < cur ? cur : list[j];
          list[j] = lo;
          cur = hi;
        }
      }
    }
  };

  for (int q = 0; q <= GRID; ++q) {
    if (q == 0) {
      scan_cell(cx, cy);
    } else {
      int x0 = cx - q, x1 = cx + q, y0 = cy - q, y1 = cy + q;
      int xa = x0 < 0 ? 0 : x0, xb_ = x1 > GRID - 1 ? GRID - 1 : x1;
      for (int ux = xa; ux <= xb_; ++ux) {
        if (y0 >= 0) scan_cell(ux, y0);
        if (y1 <= GRID - 1) scan_cell(ux, y1);
      }
      int ya = (y0 + 1) < 0 ? 0 : y0 + 1, yb = (y1 - 1) > GRID - 1 ? GRID - 1 : y1 - 1;
      for (int uy = ya; uy <= yb; ++uy) {
        if (x0 >= 0) scan_cell(x0, uy);
        if (x1 <= GRID - 1) scan_cell(x1, uy);
      }
      float bound = (float)q * (1.0f / GRID);
      float thr = bound * bound - 1e-5f;
      int cntn = 0;
#pragma unroll
      for (int j = 0; j <= KNN; ++j) {
        unsigned k32 = (unsigned)(list[j] >> 24);
        float d2v = (k32 >= 0x80000000u) ? __uint_as_float(k32 & 0x7FFFFFFFu)
                                         : -__uint_as_float(~k32);
        cntn += (list[j] != ~0ull && d2v < thr) ? 1 : 0;
      }
#pragma unroll
      for (int o = 1; o < 8; o <<= 1) cntn += __shfl_xor(cntn, o, 64);
      if (cntn >= 9) break;
    }
  }

  for (int r = 0; r <= KNN; ++r) {
    u64 cand = list[0];
    u64 mn = cand;
#pragma unroll
    for (int o = 1; o < 8; o <<= 1) {
      u64 v = __shfl_xor(mn, o, 64);
      mn = v < mn ? v : mn;
    }
    if (cand == mn) {
#pragma unroll
      for (int j = 0; j < KNN; ++j) list[j] = list[j + 1];
      list[KNN] = ~0ull;
      if (r > 0) knn_s[(size_t)gang * KNN + (r - 1)] = (int)(mn & 0xFFFull);
    }
  }
}

// ---------------------------------------------------------------------------
__global__ __launch_bounds__(256) void rev_build_kernel(const int* __restrict__ knn,
                                                        int* __restrict__ cnt,
                                                        int* __restrict__ rev,
                                                        int N, int BN) {
  int e = blockIdx.x * blockDim.x + threadIdx.x;
  if (e >= BN * KNN) return;
  int bn = e >> 3;
  int m = knn[e];
  int b = bn / N;
  int gm = b * N + m;
  int pos = atomicAdd(&cnt[gm], 1);
  if (pos < CAP) rev[(size_t)gm * CAP + pos] = bn - b * N;
}

// ---------------------------------------------------------------------------
// Initial features -> bf16, permuted to sorted order.
// ---------------------------------------------------------------------------
__global__ __launch_bounds__(128) void x2bf_perm_kernel(const float* __restrict__ x,
                                                        const int* __restrict__ sorig,
                                                        unsigned short* __restrict__ xs,
                                                        int N) {
  int row = blockIdx.x;
  int b = row / N;
  int src = b * N + sorig[row];
  int t = threadIdx.x;
  float4 v = ((const float4*)(x + (size_t)src * HIDDEN))[t];
  ushort4 o;
  o.x = f2bf(v.x); o.y = f2bf(v.y); o.z = f2bf(v.z); o.w = f2bf(v.w);
  ((ushort4*)(xs + (size_t)row * HIDDEN))[t] = o;
}

// ---------------------------------------------------------------------------
// Aggregation in sorted space (neighbors index-local -> L2 resident).
// ---------------------------------------------------------------------------
__global__ __launch_bounds__(128) void agg_kernel(const unsigned short* __restrict__ x,
                                                  const int* __restrict__ knn,
                                                  const int* __restrict__ cnt,
                                                  const int* __restrict__ rev,
                                                  unsigned short* __restrict__ aggb,
                                                  int N) {
  int bn = blockIdx.x;
  int b = bn / N;
  int t = threadIdx.x;
  const int* my = knn + (size_t)bn * KNN;
  int nb[KNN];
#pragma unroll
  for (int j = 0; j < KNN; ++j) nb[j] = my[j];
  const unsigned short* xb = x + (size_t)b * N * HIDDEN;
  float4 acc = {0.f, 0.f, 0.f, 0.f};
#pragma unroll
  for (int j = 0; j < KNN; ++j) {
    ushort4 v = ((const ushort4*)(xb + (size_t)nb[j] * HIDDEN))[t];
    acc.x += bf2f(v.x); acc.y += bf2f(v.y); acc.z += bf2f(v.z); acc.w += bf2f(v.w);
  }
  int indeg = cnt[bn];
  if (indeg > CAP) indeg = CAP;
  const int* rv = rev + (size_t)bn * CAP;
  for (int i = 0; i < indeg; ++i) {
    int r = rv[i];
    bool dup = false;
#pragma unroll
    for (int j = 0; j < KNN; ++j) dup = dup || (r == nb[j]);
    if (!dup) {
      ushort4 v = ((const ushort4*)(xb + (size_t)r * HIDDEN))[t];
      acc.x += bf2f(v.x); acc.y += bf2f(v.y); acc.z += bf2f(v.z); acc.w += bf2f(v.w);
    }
  }
  ushort4 o;
  o.x = f2bf(acc.x); o.y = f2bf(acc.y); o.z = f2bf(acc.z); o.w = f2bf(acc.w);
  ((ushort4*)(aggb + (size_t)bn * HIDDEN))[t] = o;
}

// ---------------------------------------------------------------------------
// W convert+transpose: W[l][k][n] fp32 -> Wt[l][n][k] bf16.
// ---------------------------------------------------------------------------
__global__ __launch_bounds__(256) void wconv_kernel(const float* __restrict__ W,
                                                    unsigned short* __restrict__ Wt) {
  __shared__ unsigned short tile[64][65];
  int l = blockIdx.x >> 6;
  int t6 = blockIdx.x & 63;
  int k0 = (t6 >> 3) * 64, n0 = (t6 & 7) * 64;
  const float* Wl = W + (size_t)l * HIDDEN * HIDDEN;
  unsigned short* Wtl = Wt + (size_t)l * HIDDEN * HIDDEN;
  int t = threadIdx.x;
#pragma unroll
  for (int r = 0; r < 4; ++r) {
    int row = (t >> 4) + r * 16;
    int col = (t & 15) * 4;
    float4 v = *(const float4*)(Wl + (size_t)(k0 + row) * HIDDEN + n0 + col);
    tile[col + 0][row] = f2bf(v.x);
    tile[col + 1][row] = f2bf(v.y);
    tile[col + 2][row] = f2bf(v.z);
    tile[col + 3][row] = f2bf(v.w);
  }
  __syncthreads();
#pragma unroll
  for (int r = 0; r < 4; ++r) {
    int row = (t >> 4) + r * 16;
    int col = (t & 15) * 4;
    ushort4 o;
    o.x = tile[row][col + 0]; o.y = tile[row][col + 1];
    o.z = tile[row][col + 2]; o.w = tile[row][col + 3];
    *(ushort4*)(Wtl + (size_t)(n0 + row) * HIDDEN + k0 + col) = o;
  }
}

// ---------------------------------------------------------------------------
// bf16 MFMA GEMM: tmpb = bf16(A @ W + bias). 128x128 tile, BK=32, 4 waves 2x2.
// (round-6 structure; epilogue now adds bias and stores bf16 -> halves the
// tmp round-trip HBM traffic.)
// ---------------------------------------------------------------------------
__global__ __launch_bounds__(256) void gemm_mfma_kernel(
    const unsigned short* __restrict__ A,
    const unsigned short* __restrict__ Wt,
    const float* __restrict__ bias,
    unsigned short* __restrict__ Cb) {
  __shared__ unsigned short As[128 * 40];
  __shared__ unsigned short Bs[128 * 40];
  int t = threadIdx.x;
  int n0 = blockIdx.x * 128;
  int m0 = blockIdx.y * 128;
  int w = t >> 6, lane = t & 63;
  int wr = w >> 1, wc = w & 1;
  int lm = lane & 15, q = lane >> 4;

  f32x4 acc[4][4];
#pragma unroll
  for (int i = 0; i < 4; ++i)
#pragma unroll
    for (int j = 0; j < 4; ++j) acc[i][j] = (f32x4){0.f, 0.f, 0.f, 0.f};

  int srow = t >> 2;
  int scol = (t & 3) * 8;

  for (int k0 = 0; k0 < HIDDEN; k0 += 32) {
    uint4 a0 = *(const uint4*)(A + (size_t)(m0 + srow) * HIDDEN + k0 + scol);
    uint4 a1 = *(const uint4*)(A + (size_t)(m0 + srow + 64) * HIDDEN + k0 + scol);
    uint4 b0 = *(const uint4*)(Wt + (size_t)(n0 + srow) * HIDDEN + k0 + scol);
    uint4 b1 = *(const uint4*)(Wt + (size_t)(n0 + srow + 64) * HIDDEN + k0 + scol);
    __syncthreads();
    *(uint4*)(As + srow * 40 + scol) = a0;
    *(uint4*)(As + (srow + 64) * 40 + scol) = a1;
    *(uint4*)(Bs + srow * 40 + scol) = b0;
    *(uint4*)(Bs + (srow + 64) * 40 + scol) = b1;
    __syncthreads();
    short8 af[4], bfr[4];
#pragma unroll
    for (int i = 0; i < 4; ++i)
      af[i] = *(const short8*)(As + (wr * 64 + i * 16 + lm) * 40 + q * 8);
#pragma unroll
    for (int j = 0; j < 4; ++j)
      bfr[j] = *(const short8*)(Bs + (wc * 64 + j * 16 + lm) * 40 + q * 8);
#pragma unroll
    for (int i = 0; i < 4; ++i)
#pragma unroll
      for (int j = 0; j < 4; ++j)
        acc[i][j] = __builtin_amdgcn_mfma_f32_16x16x32_bf16(af[i], bfr[j], acc[i][j], 0, 0, 0);
  }

#pragma unroll
  for (int i = 0; i < 4; ++i) {
    int row = m0 + wr * 64 + i * 16 + q * 4;
#pragma unroll
    for (int j = 0; j < 4; ++j) {
      int col = n0 + wc * 64 + j * 16 + lm;
      float bv = bias[col];
#pragma unroll
      for (int r = 0; r < 4; ++r)
        Cb[(size_t)(row + r) * HIDDEN + col] = f2bf(acc[i][j][r] + bv);
    }
  }
}

// ---------------------------------------------------------------------------
// LayerNorm + ReLU + residual, sorted space, bf16 tmp input. One wave per row;
// lane owns elements 8*lane..8*lane+7. Stats in fp32.
// final=0: xs[row] = bf16(result). final=1: out[perm(row)] = fp32 result.
// ---------------------------------------------------------------------------
__global__ __launch_bounds__(256) void ln_relu_res_kernel(
    const unsigned short* __restrict__ tb, const float* __restrict__ g,
    const float* __restrict__ be, unsigned short* __restrict__ xs,
    float* __restrict__ out, const int* __restrict__ sorig,
    int N, int addres, int final_) {
  int row = (blockIdx.x << 2) + (threadIdx.x >> 6);
  int lane = threadIdx.x & 63;
  uint4 u = ((const uint4*)(tb + (size_t)row * HIDDEN))[lane];
  float v[8];
  v[0] = bf2f((unsigned short)(u.x & 0xFFFFu)); v[1] = bf2f((unsigned short)(u.x >> 16));
  v[2] = bf2f((unsigned short)(u.y & 0xFFFFu)); v[3] = bf2f((unsigned short)(u.y >> 16));
  v[4] = bf2f((unsigned short)(u.z & 0xFFFFu)); v[5] = bf2f((unsigned short)(u.z >> 16));
  v[6] = bf2f((unsigned short)(u.w & 0xFFFFu)); v[7] = bf2f((unsigned short)(u.w >> 16));
  float s = 0.f, ss = 0.f;
#pragma unroll
  for (int k = 0; k < 8; ++k) { s += v[k]; ss += v[k] * v[k]; }
#pragma unroll
  for (int o = 32; o > 0; o >>= 1) {
    s += __shfl_xor(s, o, 64);
    ss += __shfl_xor(ss, o, 64);
  }
  float mu = s * (1.0f / HIDDEN);
  float var = ss * (1.0f / HIDDEN) - mu * mu;
  float inv = rsqrtf(var + EPSV);
  float4 g0 = ((const float4*)g)[2 * lane], g1 = ((const float4*)g)[2 * lane + 1];
  float4 b0 = ((const float4*)be)[2 * lane], b1 = ((const float4*)be)[2 * lane + 1];
  float gv[8] = {g0.x, g0.y, g0.z, g0.w, g1.x, g1.y, g1.z, g1.w};
  float bv[8] = {b0.x, b0.y, b0.z, b0.w, b1.x, b1.y, b1.z, b1.w};
  float o8[8];
#pragma unroll
  for (int k = 0; k < 8; ++k)
    o8[k] = fmaxf((v[k] - mu) * inv * gv[k] + bv[k], 0.f);
  ushort4* xrow = (ushort4*)(xs + (size_t)row * HIDDEN);
  if (addres) {
    ushort4 r0 = xrow[2 * lane], r1 = xrow[2 * lane + 1];
    o8[0] += bf2f(r0.x); o8[1] += bf2f(r0.y); o8[2] += bf2f(r0.z); o8[3] += bf2f(r0.w);
    o8[4] += bf2f(r1.x); o8[5] += bf2f(r1.y); o8[6] += bf2f(r1.z); o8[7] += bf2f(r1.w);
  }
  if (final_) {
    int b = row / N;
    size_t dst = (size_t)(b * N + sorig[row]) * HIDDEN;
    float4 w0 = {o8[0], o8[1], o8[2], o8[3]};
    float4 w1 = {o8[4], o8[5], o8[6], o8[7]};
    ((float4*)(out + dst))[2 * lane] = w0;
    ((float4*)(out + dst))[2 * lane + 1] = w1;
  } else {
    ushort4 q0, q1;
    q0.x = f2bf(o8[0]); q0.y = f2bf(o8[1]); q0.z = f2bf(o8[2]); q0.w = f2bf(o8[3]);
    q1.x = f2bf(o8[4]); q1.y = f2bf(o8[5]); q1.z = f2bf(o8[6]); q1.w = f2bf(o8[7]);
    xrow[2 * lane] = q0;
    xrow[2 * lane + 1] = q1;
  }
}

// ---------------------------------------------------------------------------
extern "C" void kernel_launch(void* const* d_in, const int* in_sizes, int n_in,
                              void* d_out, int out_size, void* d_ws, size_t ws_size,
                              hipStream_t stream) {
  const float* nf = (const float*)d_in[0];
  const float2* coords = (const float2*)d_in[1];
  const float* Wall = (const float*)d_in[2];
  const float* ball = (const float*)d_in[3];
  const float* gall = (const float*)d_in[4];
  const float* beall = (const float*)d_in[5];
  float* out = (float*)d_out;

  int BN = in_sizes[0] / HIDDEN;  // 16384
  int N = 4096;
  int B = BN / N;

  char* ws = (char*)d_ws;
  size_t off = 0;
  auto alloc = [&](size_t bytes) -> void* {
    off = (off + 255) & ~(size_t)255;
    void* p = ws + off;
    off += bytes;
    return p;
  };
  int* knn_s = (int*)alloc((size_t)BN * KNN * sizeof(int));
  int* cnt = (int*)alloc((size_t)BN * sizeof(int));
  int* rev = (int*)alloc((size_t)BN * CAP * sizeof(int));
  unsigned short* aggb = (unsigned short*)alloc((size_t)BN * HIDDEN * sizeof(unsigned short));
  unsigned short* tmpb = (unsigned short*)alloc((size_t)BN * HIDDEN * sizeof(unsigned short));
  unsigned short* Wt = (unsigned short*)alloc((size_t)NLAYERS * HIDDEN * HIDDEN * sizeof(unsigned short));
  unsigned short* xs = (unsigned short*)alloc((size_t)BN * HIDDEN * sizeof(unsigned short));
  int* cell_start = (int*)alloc((size_t)B * (NCELL + 1) * sizeof(int));
  float2* scoord = (float2*)alloc((size_t)BN * sizeof(float2));
  int* sorig = (int*)alloc((size_t)BN * sizeof(int));

  hipMemsetAsync(cnt, 0, (size_t)BN * sizeof(int), stream);
  grid_build_kernel<<<B, 1024, 0, stream>>>(coords, cell_start, scoord, sorig, N);
  knn_grid_kernel<<<(BN * 8 + 255) / 256, 256, 0, stream>>>(cell_start, scoord, sorig, knn_s, N, BN);
  rev_build_kernel<<<(BN * KNN) / 256, 256, 0, stream>>>(knn_s, cnt, rev, N, BN);
  wconv_kernel<<<NLAYERS * 64, 256, 0, stream>>>(Wall, Wt);
  x2bf_perm_kernel<<<BN, 128, 0, stream>>>(nf, sorig, xs, N);

  for (int l = 0; l < NLAYERS; ++l) {
    agg_kernel<<<BN, 128, 0, stream>>>(xs, knn_s, cnt, rev, aggb, N);
    gemm_mfma_kernel<<<dim3(HIDDEN / 128, BN / 128), 256, 0, stream>>>(
        aggb, Wt + (size_t)l * HIDDEN * HIDDEN, ball + (size_t)l * HIDDEN, tmpb);
    ln_relu_res_kernel<<<BN / 4, 256, 0, stream>>>(
        tmpb, gall + (size_t)l * HIDDEN, beall + (size_t)l * HIDDEN,
        xs, out, sorig, N, l > 0, l == NLAYERS - 1);
  }
}

// Round 9
// 282.583 us; speedup vs baseline: 1.3855x; 1.0147x over previous
//
#include <hip/hip_runtime.h>
#include <stdint.h>

#define HIDDEN 512
#define NLAYERS 3
#define KNN 8
#define CAP 64
#define EPSV 1e-5f
#define GRID 32
#define NCELL (GRID * GRID)

typedef unsigned long long u64;
typedef __attribute__((ext_vector_type(8))) short short8;   // 8 bf16 = 4 VGPRs
typedef __attribute__((ext_vector_type(4))) float f32x4;    // MFMA acc

// async global->LDS DMA, 16 B/lane; LDS dest = wave-uniform base + lane*16
#define GLL16(gp, lp)                                                         \
  __builtin_amdgcn_global_load_lds(                                           \
      (const __attribute__((address_space(1))) unsigned int*)(gp),            \
      (__attribute__((address_space(3))) unsigned int*)(lp), 16, 0, 0)

__device__ inline unsigned short f2bf(float x) {  // RNE fp32 -> bf16 bits
  union { float f; unsigned u; } v; v.f = x;
  unsigned r = v.u + 0x7FFFu + ((v.u >> 16) & 1u);
  return (unsigned short)(r >> 16);
}
__device__ inline float bf2f(unsigned short u) {
  return __uint_as_float((unsigned)u << 16);
}

// ---------------------------------------------------------------------------
// Grid build: one 1024-thread block per batch. Counting sort into 32x32 cells.
// Sorted order (scoord/sorig) is the processing order of the whole pipeline.
// ---------------------------------------------------------------------------
__global__ __launch_bounds__(1024) void grid_build_kernel(
    const float2* __restrict__ coords, int* __restrict__ cell_start,
    float2* __restrict__ scoord, int* __restrict__ sorig, int N) {
  __shared__ int hist[NCELL];
  __shared__ int offs[NCELL];
  int b = blockIdx.x;
  int t = threadIdx.x;
  hist[t] = 0;
  __syncthreads();
  const float2* cb = coords + (size_t)b * N;
  int mycell[4];
#pragma unroll
  for (int r = 0; r < 4; ++r) {
    int i = t + r * 1024;
    float2 c = cb[i];
    int cx = (int)(c.x * GRID); cx = cx < 0 ? 0 : (cx > GRID - 1 ? GRID - 1 : cx);
    int cy = (int)(c.y * GRID); cy = cy < 0 ? 0 : (cy > GRID - 1 ? GRID - 1 : cy);
    mycell[r] = cy * GRID + cx;
    atomicAdd(&hist[mycell[r]], 1);
  }
  __syncthreads();
  int v = hist[t];
  offs[t] = v;
  __syncthreads();
  for (int d = 1; d < NCELL; d <<= 1) {
    int add = (t >= d) ? offs[t - d] : 0;
    __syncthreads();
    offs[t] += add;
    __syncthreads();
  }
  int excl = offs[t] - v;
  cell_start[(size_t)b * (NCELL + 1) + t] = excl;
  if (t == 0) cell_start[(size_t)b * (NCELL + 1) + NCELL] = N;
  hist[t] = excl;
  __syncthreads();
#pragma unroll
  for (int r = 0; r < 4; ++r) {
    int i = t + r * 1024;
    int pos = atomicAdd(&hist[mycell[r]], 1);
    scoord[(size_t)b * N + pos] = cb[i];
    sorig[(size_t)b * N + pos] = i;
  }
}

// ---------------------------------------------------------------------------
// Gang-of-8 grid kNN (checker-bit-exact d2; see round-5 comments) with the
// reverse-adjacency build fused into the merge loop (owner lane atomics).
// ---------------------------------------------------------------------------
__global__ __launch_bounds__(256) void knn_grid_kernel(
    const int* __restrict__ cell_start, const float2* __restrict__ scoord,
    const int* __restrict__ sorig, int* __restrict__ knn_s,
    int* __restrict__ cnt, int* __restrict__ rev, int N, int BN) {
  int gang = (blockIdx.x * blockDim.x + threadIdx.x) >> 3;
  int sub = threadIdx.x & 7;
  if (gang >= BN) return;
  int b = gang / N;
  float2 cn = scoord[gang];
  float sqn = __fmaf_rn(cn.y, cn.y, __fmul_rn(cn.x, cn.x));
  int cx = (int)(cn.x * GRID); cx = cx < 0 ? 0 : (cx > GRID - 1 ? GRID - 1 : cx);
  int cy = (int)(cn.y * GRID); cy = cy < 0 ? 0 : (cy > GRID - 1 ? GRID - 1 : cy);
  const int* cs = cell_start + (size_t)b * (NCELL + 1);
  const float2* sc = scoord + (size_t)b * N;
  const int* so = sorig + (size_t)b * N;

  u64 list[KNN + 1];
#pragma unroll
  for (int j = 0; j <= KNN; ++j) list[j] = ~0ull;

  auto scan_cell = [&](int ux, int uy) {
    int c = uy * GRID + ux;
    int s = cs[c], e = cs[c + 1];
    for (int p = s + sub; p < e; p += 8) {
      float2 cm = sc[p];
      float sqm = __fmaf_rn(cm.y, cm.y, __fmul_rn(cm.x, cm.x));
      float dot = __fmaf_rn(cn.y, cm.y, __fmul_rn(cn.x, cm.x));
      float d2 = __fsub_rn(__fadd_rn(sqn, sqm), __fmul_rn(2.0f, dot));
      unsigned ub = __float_as_uint(d2);
      unsigned k32 = (ub & 0x80000000u) ? ~ub : (ub | 0x80000000u);
      u64 key = ((u64)k32 << 24) | ((u64)(unsigned)so[p] << 12) | (u64)(unsigned)p;
      if (key < list[KNN]) {
        u64 cur = key;
#pragma unroll
        for (int j = 0; j <= KNN; ++j) {
          u64 lo = list[j] < cur ? list[j] : cur;
          u64 hi = list[j] < cur ? cur : list[j];
          list[j] = lo;
          cur = hi;
        }
      }
    }
  };

  for (int q = 0; q <= GRID; ++q) {
    if (q == 0) {
      scan_cell(cx, cy);
    } else {
      int x0 = cx - q, x1 = cx + q, y0 = cy - q, y1 = cy + q;
      int xa = x0 < 0 ? 0 : x0, xb_ = x1 > GRID - 1 ? GRID - 1 : x1;
      for (int ux = xa; ux <= xb_; ++ux) {
        if (y0 >= 0) scan_cell(ux, y0);
        if (y1 <= GRID - 1) scan_cell(ux, y1);
      }
      int ya = (y0 + 1) < 0 ? 0 : y0 + 1, yb = (y1 - 1) > GRID - 1 ? GRID - 1 : y1 - 1;
      for (int uy = ya; uy <= yb; ++uy) {
        if (x0 >= 0) scan_cell(x0, uy);
        if (x1 <= GRID - 1) scan_cell(x1, uy);
      }
      float bound = (float)q * (1.0f / GRID);
      float thr = bound * bound - 1e-5f;
      int cntn = 0;
#pragma unroll
      for (int j = 0; j <= KNN; ++j) {
        unsigned k32 = (unsigned)(list[j] >> 24);
        float d2v = (k32 >= 0x80000000u) ? __uint_as_float(k32 & 0x7FFFFFFFu)
                                         : -__uint_as_float(~k32);
        cntn += (list[j] != ~0ull && d2v < thr) ? 1 : 0;
      }
#pragma unroll
      for (int o = 1; o < 8; o <<= 1) cntn += __shfl_xor(cntn, o, 64);
      if (cntn >= 9) break;
    }
  }

  int gl = gang - b * N;  // local sorted index of this node
  for (int r = 0; r <= KNN; ++r) {
    u64 cand = list[0];
    u64 mn = cand;
#pragma unroll
    for (int o = 1; o < 8; o <<= 1) {
      u64 v = __shfl_xor(mn, o, 64);
      mn = v < mn ? v : mn;
    }
    if (cand == mn) {
#pragma unroll
      for (int j = 0; j < KNN; ++j) list[j] = list[j + 1];
      list[KNN] = ~0ull;
      if (r > 0) {
        int m = (int)(mn & 0xFFFull);  // sorted-space neighbor
        knn_s[(size_t)gang * KNN + (r - 1)] = m;
        int gm = b * N + m;
        int pos = atomicAdd(&cnt[gm], 1);
        if (pos < CAP) rev[(size_t)gm * CAP + pos] = gl;
      }
    }
  }
}

// ---------------------------------------------------------------------------
// Initial features -> bf16, permuted to sorted order.
// ---------------------------------------------------------------------------
__global__ __launch_bounds__(128) void x2bf_perm_kernel(const float* __restrict__ x,
                                                        const int* __restrict__ sorig,
                                                        unsigned short* __restrict__ xs,
                                                        int N) {
  int row = blockIdx.x;
  int b = row / N;
  int src = b * N + sorig[row];
  int t = threadIdx.x;
  float4 v = ((const float4*)(x + (size_t)src * HIDDEN))[t];
  ushort4 o;
  o.x = f2bf(v.x); o.y = f2bf(v.y); o.z = f2bf(v.z); o.w = f2bf(v.w);
  ((ushort4*)(xs + (size_t)row * HIDDEN))[t] = o;
}

// ---------------------------------------------------------------------------
// Aggregation in sorted space (neighbors index-local -> L2 resident).
// ---------------------------------------------------------------------------
__global__ __launch_bounds__(128) void agg_kernel(const unsigned short* __restrict__ x,
                                                  const int* __restrict__ knn,
                                                  const int* __restrict__ cnt,
                                                  const int* __restrict__ rev,
                                                  unsigned short* __restrict__ aggb,
                                                  int N) {
  int bn = blockIdx.x;
  int b = bn / N;
  int t = threadIdx.x;
  const int* my = knn + (size_t)bn * KNN;
  int nb[KNN];
#pragma unroll
  for (int j = 0; j < KNN; ++j) nb[j] = my[j];
  const unsigned short* xb = x + (size_t)b * N * HIDDEN;
  float4 acc = {0.f, 0.f, 0.f, 0.f};
#pragma unroll
  for (int j = 0; j < KNN; ++j) {
    ushort4 v = ((const ushort4*)(xb + (size_t)nb[j] * HIDDEN))[t];
    acc.x += bf2f(v.x); acc.y += bf2f(v.y); acc.z += bf2f(v.z); acc.w += bf2f(v.w);
  }
  int indeg = cnt[bn];
  if (indeg > CAP) indeg = CAP;
  const int* rv = rev + (size_t)bn * CAP;
  for (int i = 0; i < indeg; ++i) {
    int r = rv[i];
    bool dup = false;
#pragma unroll
    for (int j = 0; j < KNN; ++j) dup = dup || (r == nb[j]);
    if (!dup) {
      ushort4 v = ((const ushort4*)(xb + (size_t)r * HIDDEN))[t];
      acc.x += bf2f(v.x); acc.y += bf2f(v.y); acc.z += bf2f(v.z); acc.w += bf2f(v.w);
    }
  }
  ushort4 o;
  o.x = f2bf(acc.x); o.y = f2bf(acc.y); o.z = f2bf(acc.z); o.w = f2bf(acc.w);
  ((ushort4*)(aggb + (size_t)bn * HIDDEN))[t] = o;
}

// ---------------------------------------------------------------------------
// W convert+transpose: W[l][k][n] fp32 -> Wt[l][n][k] bf16.
// ---------------------------------------------------------------------------
__global__ __launch_bounds__(256) void wconv_kernel(const float* __restrict__ W,
                                                    unsigned short* __restrict__ Wt) {
  __shared__ unsigned short tile[64][65];
  int l = blockIdx.x >> 6;
  int t6 = blockIdx.x & 63;
  int k0 = (t6 >> 3) * 64, n0 = (t6 & 7) * 64;
  const float* Wl = W + (size_t)l * HIDDEN * HIDDEN;
  unsigned short* Wtl = Wt + (size_t)l * HIDDEN * HIDDEN;
  int t = threadIdx.x;
#pragma unroll
  for (int r = 0; r < 4; ++r) {
    int row = (t >> 4) + r * 16;
    int col = (t & 15) * 4;
    float4 v = *(const float4*)(Wl + (size_t)(k0 + row) * HIDDEN + n0 + col);
    tile[col + 0][row] = f2bf(v.x);
    tile[col + 1][row] = f2bf(v.y);
    tile[col + 2][row] = f2bf(v.z);
    tile[col + 3][row] = f2bf(v.w);
  }
  __syncthreads();
#pragma unroll
  for (int r = 0; r < 4; ++r) {
    int row = (t >> 4) + r * 16;
    int col = (t & 15) * 4;
    ushort4 o;
    o.x = tile[row][col + 0]; o.y = tile[row][col + 1];
    o.z = tile[row][col + 2]; o.w = tile[row][col + 3];
    *(ushort4*)(Wtl + (size_t)(n0 + row) * HIDDEN + k0 + col) = o;
  }
}

// ---------------------------------------------------------------------------
// bf16 MFMA GEMM: tmpb = bf16(A @ W + bias). 128x128 tile, BK=32, 4 waves 2x2.
// Staging via global_load_lds width=16 (m97 structure): unpadded 64 B LDS
// rows (DMA lane mapping = wave-uniform base + lane*16; no padding allowed).
// Each wave stages 2 chunks of As + 2 of Bs per K-step (1 KB each: 16 rows,
// lane i -> row i/4, col 8*(i%4)). ds_read_b128 at 32-elem stride: lanes
// split into 8 (q, row-parity) groups x 4 banks -> even 8-cycle service.
// ---------------------------------------------------------------------------
__global__ __launch_bounds__(256) void gemm_mfma_kernel(
    const unsigned short* __restrict__ A,
    const unsigned short* __restrict__ Wt,
    const float* __restrict__ bias,
    unsigned short* __restrict__ Cb) {
  __shared__ unsigned short As[128 * 32];
  __shared__ unsigned short Bs[128 * 32];
  int t = threadIdx.x;
  int n0 = blockIdx.x * 128;
  int m0 = blockIdx.y * 128;
  int w = t >> 6, lane = t & 63;
  int wr = w >> 1, wc = w & 1;
  int lm = lane & 15, q = lane >> 4;

  f32x4 acc[4][4];
#pragma unroll
  for (int i = 0; i < 4; ++i)
#pragma unroll
    for (int j = 0; j < 4; ++j) acc[i][j] = (f32x4){0.f, 0.f, 0.f, 0.f};

  int lrow = lane >> 2;        // 0..15 within a 16-row chunk
  int lcol = (lane & 3) * 8;   // 0,8,16,24
  int e0 = w, e1 = w + 4;      // chunk ids this wave stages

  const unsigned short* Arow0 = A + (size_t)(m0 + e0 * 16 + lrow) * HIDDEN + lcol;
  const unsigned short* Arow1 = A + (size_t)(m0 + e1 * 16 + lrow) * HIDDEN + lcol;
  const unsigned short* Brow0 = Wt + (size_t)(n0 + e0 * 16 + lrow) * HIDDEN + lcol;
  const unsigned short* Brow1 = Wt + (size_t)(n0 + e1 * 16 + lrow) * HIDDEN + lcol;

  for (int k0 = 0; k0 < HIDDEN; k0 += 32) {
    __syncthreads();  // prior-iter LDS reads done before DMA overwrite
    GLL16(Arow0 + k0, As + e0 * 16 * 32);
    GLL16(Arow1 + k0, As + e1 * 16 * 32);
    GLL16(Brow0 + k0, Bs + e0 * 16 * 32);
    GLL16(Brow1 + k0, Bs + e1 * 16 * 32);
    __syncthreads();  // vmcnt(0) drain (DMA complete) + barrier
    short8 af[4], bfr[4];
#pragma unroll
    for (int i = 0; i < 4; ++i)
      af[i] = *(const short8*)(As + (wr * 64 + i * 16 + lm) * 32 + q * 8);
#pragma unroll
    for (int j = 0; j < 4; ++j)
      bfr[j] = *(const short8*)(Bs + (wc * 64 + j * 16 + lm) * 32 + q * 8);
#pragma unroll
    for (int i = 0; i < 4; ++i)
#pragma unroll
      for (int j = 0; j < 4; ++j)
        acc[i][j] = __builtin_amdgcn_mfma_f32_16x16x32_bf16(af[i], bfr[j], acc[i][j], 0, 0, 0);
  }

#pragma unroll
  for (int i = 0; i < 4; ++i) {
    int row = m0 + wr * 64 + i * 16 + q * 4;
#pragma unroll
    for (int j = 0; j < 4; ++j) {
      int col = n0 + wc * 64 + j * 16 + lm;
      float bv = bias[col];
#pragma unroll
      for (int r = 0; r < 4; ++r)
        Cb[(size_t)(row + r) * HIDDEN + col] = f2bf(acc[i][j][r] + bv);
    }
  }
}

// ---------------------------------------------------------------------------
// LayerNorm + ReLU + residual, sorted space, bf16 tmp input. One wave per row;
// lane owns elements 8*lane..8*lane+7. Stats in fp32.
// final=0: xs[row] = bf16(result). final=1: out[perm(row)] = fp32 result.
// ---------------------------------------------------------------------------
__global__ __launch_bounds__(256) void ln_relu_res_kernel(
    const unsigned short* __restrict__ tb, const float* __restrict__ g,
    const float* __restrict__ be, unsigned short* __restrict__ xs,
    float* __restrict__ out, const int* __restrict__ sorig,
    int N, int addres, int final_) {
  int row = (blockIdx.x << 2) + (threadIdx.x >> 6);
  int lane = threadIdx.x & 63;
  uint4 u = ((const uint4*)(tb + (size_t)row * HIDDEN))[lane];
  float v[8];
  v[0] = bf2f((unsigned short)(u.x & 0xFFFFu)); v[1] = bf2f((unsigned short)(u.x >> 16));
  v[2] = bf2f((unsigned short)(u.y & 0xFFFFu)); v[3] = bf2f((unsigned short)(u.y >> 16));
  v[4] = bf2f((unsigned short)(u.z & 0xFFFFu)); v[5] = bf2f((unsigned short)(u.z >> 16));
  v[6] = bf2f((unsigned short)(u.w & 0xFFFFu)); v[7] = bf2f((unsigned short)(u.w >> 16));
  float s = 0.f, ss = 0.f;
#pragma unroll
  for (int k = 0; k < 8; ++k) { s += v[k]; ss += v[k] * v[k]; }
#pragma unroll
  for (int o = 32; o > 0; o >>= 1) {
    s += __shfl_xor(s, o, 64);
    ss += __shfl_xor(ss, o, 64);
  }
  float mu = s * (1.0f / HIDDEN);
  float var = ss * (1.0f / HIDDEN) - mu * mu;
  float inv = rsqrtf(var + EPSV);
  float4 g0 = ((const float4*)g)[2 * lane], g1 = ((const float4*)g)[2 * lane + 1];
  float4 b0 = ((const float4*)be)[2 * lane], b1 = ((const float4*)be)[2 * lane + 1];
  float gv[8] = {g0.x, g0.y, g0.z, g0.w, g1.x, g1.y, g1.z, g1.w};
  float bv[8] = {b0.x, b0.y, b0.z, b0.w, b1.x, b1.y, b1.z, b1.w};
  float o8[8];
#pragma unroll
  for (int k = 0; k < 8; ++k)
    o8[k] = fmaxf((v[k] - mu) * inv * gv[k] + bv[k], 0.f);
  ushort4* xrow = (ushort4*)(xs + (size_t)row * HIDDEN);
  if (addres) {
    ushort4 r0 = xrow[2 * lane], r1 = xrow[2 * lane + 1];
    o8[0] += bf2f(r0.x); o8[1] += bf2f(r0.y); o8[2] += bf2f(r0.z); o8[3] += bf2f(r0.w);
    o8[4] += bf2f(r1.x); o8[5] += bf2f(r1.y); o8[6] += bf2f(r1.z); o8[7] += bf2f(r1.w);
  }
  if (final_) {
    int b = row / N;
    size_t dst = (size_t)(b * N + sorig[row]) * HIDDEN;
    float4 w0 = {o8[0], o8[1], o8[2], o8[3]};
    float4 w1 = {o8[4], o8[5], o8[6], o8[7]};
    ((float4*)(out + dst))[2 * lane] = w0;
    ((float4*)(out + dst))[2 * lane + 1] = w1;
  } else {
    ushort4 q0, q1;
    q0.x = f2bf(o8[0]); q0.y = f2bf(o8[1]); q0.z = f2bf(o8[2]); q0.w = f2bf(o8[3]);
    q1.x = f2bf(o8[4]); q1.y = f2bf(o8[5]); q1.z = f2bf(o8[6]); q1.w = f2bf(o8[7]);
    xrow[2 * lane] = q0;
    xrow[2 * lane + 1] = q1;
  }
}

// ---------------------------------------------------------------------------
extern "C" void kernel_launch(void* const* d_in, const int* in_sizes, int n_in,
                              void* d_out, int out_size, void* d_ws, size_t ws_size,
                              hipStream_t stream) {
  const float* nf = (const float*)d_in[0];
  const float2* coords = (const float2*)d_in[1];
  const float* Wall = (const float*)d_in[2];
  const float* ball = (const float*)d_in[3];
  const float* gall = (const float*)d_in[4];
  const float* beall = (const float*)d_in[5];
  float* out = (float*)d_out;

  int BN = in_sizes[0] / HIDDEN;  // 16384
  int N = 4096;
  int B = BN / N;

  char* ws = (char*)d_ws;
  size_t off = 0;
  auto alloc = [&](size_t bytes) -> void* {
    off = (off + 255) & ~(size_t)255;
    void* p = ws + off;
    off += bytes;
    return p;
  };
  int* knn_s = (int*)alloc((size_t)BN * KNN * sizeof(int));
  int* cnt = (int*)alloc((size_t)BN * sizeof(int));
  int* rev = (int*)alloc((size_t)BN * CAP * sizeof(int));
  unsigned short* aggb = (unsigned short*)alloc((size_t)BN * HIDDEN * sizeof(unsigned short));
  unsigned short* tmpb = (unsigned short*)alloc((size_t)BN * HIDDEN * sizeof(unsigned short));
  unsigned short* Wt = (unsigned short*)alloc((size_t)NLAYERS * HIDDEN * HIDDEN * sizeof(unsigned short));
  unsigned short* xs = (unsigned short*)alloc((size_t)BN * HIDDEN * sizeof(unsigned short));
  int* cell_start = (int*)alloc((size_t)B * (NCELL + 1) * sizeof(int));
  float2* scoord = (float2*)alloc((size_t)BN * sizeof(float2));
  int* sorig = (int*)alloc((size_t)BN * sizeof(int));

  hipMemsetAsync(cnt, 0, (size_t)BN * sizeof(int), stream);
  grid_build_kernel<<<B, 1024, 0, stream>>>(coords, cell_start, scoord, sorig, N);
  knn_grid_kernel<<<(BN * 8 + 255) / 256, 256, 0, stream>>>(cell_start, scoord, sorig, knn_s, cnt, rev, N, BN);
  wconv_kernel<<<NLAYERS * 64, 256, 0, stream>>>(Wall, Wt);
  x2bf_perm_kernel<<<BN, 128, 0, stream>>>(nf, sorig, xs, N);

  for (int l = 0; l < NLAYERS; ++l) {
    agg_kernel<<<BN, 128, 0, stream>>>(xs, knn_s, cnt, rev, aggb, N);
    gemm_mfma_kernel<<<dim3(HIDDEN / 128, BN / 128), 256, 0, stream>>>(
        aggb, Wt + (size_t)l * HIDDEN * HIDDEN, ball + (size_t)l * HIDDEN, tmpb);
    ln_relu_res_kernel<<<BN / 4, 256, 0, stream>>>(
        tmpb, gall + (size_t)l * HIDDEN, beall + (size_t)l * HIDDEN,
        xs, out, sorig, N, l > 0, l == NLAYERS - 1);
  }
}